// Round 1
// 646.785 us; speedup vs baseline: 1.1012x; 1.1012x over previous
//
#include <hip/hip_runtime.h>
#include <math.h>

typedef float f4 __attribute__((ext_vector_type(4)));

constexpr int kB = 64;
constexpr int kLs = 256;
constexpr int kM = 4;
constexpr int kLw = 256;
constexpr int kLy = 128;
constexpr int kHid = 512;
constexpr int kSteps = 6;
constexpr float kEps = 1e-5f;

__device__ __forceinline__ float wred(float v) {
#pragma unroll
  for (int off = 32; off > 0; off >>= 1) v += __shfl_down(v, off, 64);
  return v;
}

// h_static[b,m,hid] = b1[hid] + sum_l wy[b,m,l] * W1[512+l, hid]   (once)
__global__ __launch_bounds__(256) void k_static(
    const float* __restrict__ wr, const float* __restrict__ wi,
    const float* __restrict__ yy, const float* __restrict__ W1,
    const float* __restrict__ b1, float* __restrict__ hstat) {
  const int b = blockIdx.x >> 1;
  const int hid = ((blockIdx.x & 1) << 8) + threadIdx.x;
  const float* w1c = W1 + hid;
  f4 acc = {0.f, 0.f, 0.f, 0.f};
#pragma unroll 4
  for (int l = 0; l < kLw; ++l) {
    const float w1v = w1c[(size_t)(2 * kLs + l) * kHid];
    const f4 w = *(const f4*)(wr + ((size_t)b * kLw + l) * kM);
#pragma unroll
    for (int m = 0; m < kM; ++m) acc[m] += w[m] * w1v;
  }
#pragma unroll 4
  for (int l = 0; l < kLw; ++l) {
    const float w1v = w1c[(size_t)(2 * kLs + kLw + l) * kHid];
    const f4 w = *(const f4*)(wi + ((size_t)b * kLw + l) * kM);
#pragma unroll
    for (int m = 0; m < kM; ++m) acc[m] += w[m] * w1v;
  }
#pragma unroll 4
  for (int l = 0; l < kLy; ++l) {
    const float w1v = w1c[(size_t)(2 * kLs + 2 * kLw + l) * kHid];
    const f4 w = *(const f4*)(yy + ((size_t)b * kLy + l) * kM);
#pragma unroll
    for (int m = 0; m < kM; ++m) acc[m] += w[m] * w1v;
  }
  const float bv = b1[hid];
#pragma unroll
  for (int m = 0; m < kM; ++m)
    hstat[((size_t)b * kM + m) * kHid + hid] = acc[m] + bv;
}

// Seed s = exp(i*phi) for step 0 + write outS[step 0].
__global__ __launch_bounds__(256) void k_s0(
    const float* __restrict__ phi, float* __restrict__ sReg,
    float* __restrict__ sImg, float* __restrict__ outSR,
    float* __restrict__ outSI) {
  const int b = blockIdx.x, t = threadIdx.x;
  float sn, cs;
  sincosf(phi[b * kLs + t], &sn, &cs);
  sReg[b * kLs + t] = cs;
  sImg[b * kLs + t] = sn;
  const size_t oo = ((size_t)b * (kSteps + 1)) * kLs + t;
  outSR[oo] = cs;
  outSI[oo] = sn;
}

// Double-buffered row pipeline state: one row = 16 KB (16 f4 per lane).
typedef struct {
  f4 gr[4], gi[4], hr[4], hi[4];
} RowBuf;

__device__ __forceinline__ void load_row(RowBuf& rb, const float* __restrict__ grp,
                                         const float* __restrict__ gip,
                                         const float* __restrict__ hrp,
                                         const float* __restrict__ hip_, int r) {
#pragma unroll
  for (int rr = 0; rr < 4; ++rr) {
    const size_t off = (size_t)r * (kLs * kM) + (size_t)(rr * 64) * kM;
    rb.gr[rr] = *(const f4*)(grp + off);
    rb.gi[rr] = *(const f4*)(gip + off);
    rb.hr[rr] = *(const f4*)(hrp + off);
    rb.hi[rr] = *(const f4*)(hip_ + off);
  }
}

__device__ __forceinline__ void compute_row(
    const RowBuf& rb, const float* s_r, const float* s_i,
    float* __restrict__ gsR, float* __restrict__ gsI,
    float* __restrict__ hsR, float* __restrict__ hsI,
    size_t obase, int r, int lane) {
  f4 aGr = {0, 0, 0, 0}, aGi = {0, 0, 0, 0};
  f4 aHr = {0, 0, 0, 0}, aHi = {0, 0, 0, 0};
#pragma unroll
  for (int rr = 0; rr < 4; ++rr) {
    const float sr = s_r[rr], si = s_i[rr];
#pragma unroll
    for (int m = 0; m < kM; ++m) {
      aGr[m] += rb.gr[rr][m] * sr - rb.gi[rr][m] * si;
      aGi[m] += rb.gr[rr][m] * si + rb.gi[rr][m] * sr;
      aHr[m] += rb.hr[rr][m] * sr - rb.hi[rr][m] * si;
      aHi[m] += rb.hr[rr][m] * si + rb.hi[rr][m] * sr;
    }
  }
#pragma unroll
  for (int m = 0; m < kM; ++m) {
    aGr[m] = wred(aGr[m]);
    aGi[m] = wred(aGi[m]);
    aHr[m] = wred(aHr[m]);
    aHi[m] = wred(aHi[m]);
  }
  if (lane == 0) {
    const size_t o = obase + (size_t)r * kM;
    *(f4*)(gsR + o) = aGr;
    *(f4*)(gsI + o) = aGi;
    *(f4*)(hsR + o) = aHr;
    *(f4*)(hsI + o) = aHi;
  }
}

// Per-step heavy kernel.
// Blocks 0..127: h_dyn[b,hid] (launched first; W1 stream hides under matvec).
// Blocks 128..639: matvec. One wave streams 8 rows (128 KB), double-buffered:
//   row r+1's 16 dwordx4 loads are in flight while row r is FMA'd + reduced.
//   No sincos / LDS / syncthreads here — s comes precomputed from global.
__global__ __launch_bounds__(256, 2) void k_step_main(
    const float* __restrict__ Gr, const float* __restrict__ Gi,
    const float* __restrict__ Hr, const float* __restrict__ Hi,
    const float* __restrict__ W1, const float* __restrict__ sReg,
    const float* __restrict__ sImg, float* __restrict__ gsR,
    float* __restrict__ gsI, float* __restrict__ hsR,
    float* __restrict__ hsI, float* __restrict__ hdyn) {
  const int t = threadIdx.x;
  const int blk = blockIdx.x;

  if (blk < kB * 2) {  // ---- hdyn path ----
    const int b = blk >> 1;
    const int hid = ((blk & 1) << 8) + t;
    const float* w1c = W1 + hid;
    const float* sr = sReg + b * kLs;
    const float* si = sImg + b * kLs;
    float acc = 0.f;
#pragma unroll 8
    for (int j = 0; j < kLs; ++j) {
      acc += sr[j] * w1c[(size_t)j * kHid];
      acc += si[j] * w1c[(size_t)(j + kLs) * kHid];
    }
    hdyn[b * kHid + hid] = acc;
    return;
  }

  // ---- matvec path ----
  const int mb = blk - kB * 2;            // 0..511
  const int lane = t & 63;
  const int wv = t >> 6;
  const int b = mb >> 3;
  const int i0 = ((mb & 7) << 5) + (wv << 3);  // this wave's 8 rows
  const size_t row0 = ((size_t)b * kLs + i0) * (kLs * kM) + (size_t)lane * kM;
  const float* grp = Gr + row0;
  const float* gip = Gi + row0;
  const float* hrp = Hr + row0;
  const float* hip_ = Hi + row0;
  const size_t obase = ((size_t)b * kLs + i0) * kM;

  RowBuf A, B;
  load_row(A, grp, gip, hrp, hip_, 0);  // row 0 in flight first
  float s_r[4], s_i[4];
#pragma unroll
  for (int rr = 0; rr < 4; ++rr) {
    s_r[rr] = sReg[b * kLs + (rr << 6) + lane];
    s_i[rr] = sImg[b * kLs + (rr << 6) + lane];
  }
  __builtin_amdgcn_sched_barrier(0);
#pragma unroll
  for (int r = 0; r < 8; r += 2) {
    load_row(B, grp, gip, hrp, hip_, r + 1);
    __builtin_amdgcn_sched_barrier(0);
    compute_row(A, s_r, s_i, gsR, gsI, hsR, hsI, obase, r, lane);
    __builtin_amdgcn_sched_barrier(0);
    if (r + 2 < 8) {
      load_row(A, grp, gip, hrp, hip_, r + 2);
      __builtin_amdgcn_sched_barrier(0);
    }
    compute_row(B, s_r, s_i, gsR, gsI, hsR, hsI, obase, r + 1, lane);
    __builtin_amdgcn_sched_barrier(0);
  }
}

// BN batch stats over b for each (m,hid). grid: 8 blocks x 256 threads.
__global__ __launch_bounds__(256) void k_bn(
    const float* __restrict__ hdyn, const float* __restrict__ hstat,
    float* __restrict__ mu_g, float* __restrict__ rs_g) {
  const int q = blockIdx.x * 256 + threadIdx.x;  // 0..2047
  const int m = q >> 9;
  const int hid = q & (kHid - 1);
  float sum = 0.f, ss = 0.f;
#pragma unroll 8
  for (int bb = 0; bb < kB; ++bb) {
    const float h = hdyn[bb * kHid + hid] + hstat[((size_t)bb * kM + m) * kHid + hid];
    sum += h;
    ss += h * h;
  }
  const float mu = sum * (1.f / kB);
  const float var = ss * (1.f / kB) - mu * mu;
  mu_g[q] = mu;
  rs_g[q] = rsqrtf(var + kEps);
}

// Per-step tail: one block per b. sGs/sHs, rho, eta_net, phi update,
// plus s(step+1) = exp(i*phi_new) and outS[step+1].
__global__ __launch_bounds__(256) void k_step_finish(
    const float* __restrict__ gsR, const float* __restrict__ gsI,
    const float* __restrict__ hsR, const float* __restrict__ hsI,
    const float* __restrict__ hdyn, const float* __restrict__ hstat,
    const float* __restrict__ mu_g, const float* __restrict__ rs_g,
    const float* __restrict__ gamma_, const float* __restrict__ beta_,
    const float* __restrict__ W2, const float* __restrict__ b2,
    float* __restrict__ phi, float* __restrict__ sReg, float* __restrict__ sImg,
    float* __restrict__ outSR, float* __restrict__ outSI,
    float* __restrict__ outRho, int step) {
  const int b = blockIdx.x, t = threadIdx.x;
  const int lane = t & 63, wv = t >> 6;
  __shared__ float red[4][16];
  __shared__ float sgR[4], sgI[4], shR[4], shI[4], c2[4];
  __shared__ float rho_s[4];

  const int idx = b * kLs + t;
  const float p = phi[idx];
  const float cs = sReg[idx];
  const float sn = sImg[idx];

  const size_t o = (size_t)idx * kM;
  const f4 gR = *(const f4*)(gsR + o);
  const f4 gI = *(const f4*)(gsI + o);
  const f4 hR = *(const f4*)(hsR + o);
  const f4 hI = *(const f4*)(hsI + o);

  // partials of sGs = sum_i conj(s_i)*Gs[i], sHs likewise
  float v[16];
#pragma unroll
  for (int m = 0; m < kM; ++m) {
    v[m] = cs * gR[m] + sn * gI[m];       // Re(conj(s)*Gs)
    v[4 + m] = cs * gI[m] - sn * gR[m];   // Im(conj(s)*Gs)
    v[8 + m] = cs * hR[m] + sn * hI[m];
    v[12 + m] = cs * hI[m] - sn * hR[m];
  }
#pragma unroll
  for (int k = 0; k < 16; ++k) v[k] = wred(v[k]);
  if (lane == 0) {
#pragma unroll
    for (int k = 0; k < 16; ++k) red[wv][k] = v[k];
  }
  __syncthreads();
  if (t == 0) {
#pragma unroll
    for (int m = 0; m < kM; ++m) {
      const float gr = red[0][m] + red[1][m] + red[2][m] + red[3][m];
      const float gi = red[0][4 + m] + red[1][4 + m] + red[2][4 + m] + red[3][4 + m];
      const float hr = red[0][8 + m] + red[1][8 + m] + red[2][8 + m] + red[3][8 + m];
      const float hi = red[0][12 + m] + red[1][12 + m] + red[2][12 + m] + red[3][12 + m];
      sgR[m] = gr; sgI[m] = gi; shR[m] = hr; shI[m] = hi;
      const float xr = hr * hr - hi * hi;   // Re(sHs^2)
      const float xi = 2.f * hr * hi;       // Im(sHs^2)
      c2[m] = 2.f * xr / (xr * xr + xi * xi);  // Re(2/sHs^2)
    }
  }
  __syncthreads();

  // rho[b,m] = sigmoid( relu(bn(h)) . W2 + b2 )
  float pm[4] = {0.f, 0.f, 0.f, 0.f};
#pragma unroll
  for (int kk = 0; kk < 2; ++kk) {
    const int hid = (kk << 8) + t;
    const float hd = hdyn[b * kHid + hid];
    const float ga = gamma_[hid], be = beta_[hid], w2 = W2[hid];
#pragma unroll
    for (int m = 0; m < kM; ++m) {
      const float h = hd + hstat[((size_t)b * kM + m) * kHid + hid];
      const int q = m * kHid + hid;
      float hn = ga * (h - mu_g[q]) * rs_g[q] + be;
      hn = fmaxf(hn, 0.f);
      pm[m] += hn * w2;
    }
  }
#pragma unroll
  for (int m = 0; m < kM; ++m) pm[m] = wred(pm[m]);
  if (lane == 0) {
#pragma unroll
    for (int m = 0; m < kM; ++m) red[wv][m] = pm[m];
  }
  __syncthreads();
  if (t < 4) {
    const float tot = red[0][t] + red[1][t] + red[2][t] + red[3][t] + b2[0];
    const float r = 1.f / (1.f + expf(-tot));
    rho_s[t] = r;
    outRho[((size_t)b * kSteps + step) * kM + t] = r;
  }
  __syncthreads();

  // eta_net[b,i=t] = sum_m c2[m] * Im((sHs*Gs - sGs*Hs)*conj(s_i)) * rho[m]
  float en = 0.f;
#pragma unroll
  for (int m = 0; m < kM; ++m) {
    const float ar = shR[m] * gR[m] - shI[m] * gI[m] - (sgR[m] * hR[m] - sgI[m] * hI[m]);
    const float ai = shR[m] * gI[m] + shI[m] * gR[m] - (sgR[m] * hI[m] + sgI[m] * hR[m]);
    en += c2[m] * (ai * cs - ar * sn) * rho_s[m];
  }
  const float pn = p - en;
  phi[idx] = pn;
  float sn2, cs2;
  sincosf(pn, &sn2, &cs2);
  sReg[idx] = cs2;
  sImg[idx] = sn2;
  const size_t oo = ((size_t)b * (kSteps + 1) + step + 1) * kLs + t;
  outSR[oo] = cs2;
  outSI[oo] = sn2;
}

extern "C" void kernel_launch(void* const* d_in, const int* in_sizes, int n_in,
                              void* d_out, int out_size, void* d_ws, size_t ws_size,
                              hipStream_t stream) {
  const float* phi_in = (const float*)d_in[0];
  const float* w_real = (const float*)d_in[1];
  const float* w_imag = (const float*)d_in[2];
  const float* y = (const float*)d_in[3];
  const float* G_real = (const float*)d_in[4];
  const float* G_imag = (const float*)d_in[5];
  const float* H_real = (const float*)d_in[6];
  const float* H_imag = (const float*)d_in[7];
  const float* W1 = (const float*)d_in[8];
  const float* b1 = (const float*)d_in[9];
  const float* gamma_ = (const float*)d_in[10];
  const float* beta_ = (const float*)d_in[11];
  const float* W2 = (const float*)d_in[12];
  const float* b2 = (const float*)d_in[13];

  float* ws = (float*)d_ws;
  float* phi = ws;                    // 16384
  float* gsR = phi + kB * kLs;        // 65536 each
  float* gsI = gsR + kB * kLs * kM;
  float* hsR = gsI + kB * kLs * kM;
  float* hsI = hsR + kB * kLs * kM;
  float* hdyn = hsI + kB * kLs * kM;  // 32768
  float* hstat = hdyn + kB * kHid;    // 131072
  float* mu_g = hstat + (size_t)kB * kM * kHid;  // 2048
  float* rs_g = mu_g + kM * kHid;                // 2048
  float* sReg = rs_g + kM * kHid;                // 16384
  float* sImg = sReg + kB * kLs;                 // 16384

  float* out = (float*)d_out;
  float* outSR = out;
  float* outSI = out + (size_t)kB * (kSteps + 1) * kLs;
  float* outRho = out + 2 * (size_t)kB * (kSteps + 1) * kLs;

  hipMemcpyAsync(phi, phi_in, (size_t)kB * kLs * sizeof(float),
                 hipMemcpyDeviceToDevice, stream);
  k_static<<<dim3(kB * 2), dim3(256), 0, stream>>>(w_real, w_imag, y, W1, b1, hstat);
  k_s0<<<dim3(kB), dim3(256), 0, stream>>>(phi, sReg, sImg, outSR, outSI);
  for (int step = 0; step < kSteps; ++step) {
    k_step_main<<<dim3(kB * 2 + kB * kLs / 32), dim3(256), 0, stream>>>(
        G_real, G_imag, H_real, H_imag, W1, sReg, sImg, gsR, gsI, hsR, hsI, hdyn);
    k_bn<<<dim3(kM * kHid / 256), dim3(256), 0, stream>>>(hdyn, hstat, mu_g, rs_g);
    k_step_finish<<<dim3(kB), dim3(256), 0, stream>>>(
        gsR, gsI, hsR, hsI, hdyn, hstat, mu_g, rs_g, gamma_, beta_, W2, b2,
        phi, sReg, sImg, outSR, outSI, outRho, step);
  }
}

// Round 2
// 623.143 us; speedup vs baseline: 1.1430x; 1.0379x over previous
//
#include <hip/hip_runtime.h>
#include <math.h>

typedef float f4 __attribute__((ext_vector_type(4)));

constexpr int kB = 64;
constexpr int kLs = 256;
constexpr int kM = 4;
constexpr int kLw = 256;
constexpr int kLy = 128;
constexpr int kHid = 512;
constexpr int kSteps = 6;
constexpr float kEps = 1e-5f;

__device__ __forceinline__ float wred(float v) {
#pragma unroll
  for (int off = 32; off > 0; off >>= 1) v += __shfl_down(v, off, 64);
  return v;
}

// h_static[b,m,hid] = b1[hid] + sum_l wy[b,m,l] * W1[512+l, hid]   (once)
__global__ __launch_bounds__(256) void k_static(
    const float* __restrict__ wr, const float* __restrict__ wi,
    const float* __restrict__ yy, const float* __restrict__ W1,
    const float* __restrict__ b1, float* __restrict__ hstat) {
  const int b = blockIdx.x >> 1;
  const int hid = ((blockIdx.x & 1) << 8) + threadIdx.x;
  const float* w1c = W1 + hid;
  f4 acc = {0.f, 0.f, 0.f, 0.f};
#pragma unroll 4
  for (int l = 0; l < kLw; ++l) {
    const float w1v = w1c[(size_t)(2 * kLs + l) * kHid];
    const f4 w = *(const f4*)(wr + ((size_t)b * kLw + l) * kM);
#pragma unroll
    for (int m = 0; m < kM; ++m) acc[m] += w[m] * w1v;
  }
#pragma unroll 4
  for (int l = 0; l < kLw; ++l) {
    const float w1v = w1c[(size_t)(2 * kLs + kLw + l) * kHid];
    const f4 w = *(const f4*)(wi + ((size_t)b * kLw + l) * kM);
#pragma unroll
    for (int m = 0; m < kM; ++m) acc[m] += w[m] * w1v;
  }
#pragma unroll 4
  for (int l = 0; l < kLy; ++l) {
    const float w1v = w1c[(size_t)(2 * kLs + 2 * kLw + l) * kHid];
    const f4 w = *(const f4*)(yy + ((size_t)b * kLy + l) * kM);
#pragma unroll
    for (int m = 0; m < kM; ++m) acc[m] += w[m] * w1v;
  }
  const float bv = b1[hid];
#pragma unroll
  for (int m = 0; m < kM; ++m)
    hstat[((size_t)b * kM + m) * kHid + hid] = acc[m] + bv;
}

// Seed s = exp(i*phi) for step 0 + write outS[step 0].
__global__ __launch_bounds__(256) void k_s0(
    const float* __restrict__ phi, float* __restrict__ sReg,
    float* __restrict__ sImg, float* __restrict__ outSR,
    float* __restrict__ outSI) {
  const int b = blockIdx.x, t = threadIdx.x;
  float sn, cs;
  sincosf(phi[b * kLs + t], &sn, &cs);
  sReg[b * kLs + t] = cs;
  sImg[b * kLs + t] = sn;
  const size_t oo = ((size_t)b * (kSteps + 1)) * kLs + t;
  outSR[oo] = cs;
  outSI[oo] = sn;
}

// Per-step heavy kernel.
// Blocks 0..127: h_dyn[b,hid].
// Blocks 128..2175: matvec. One wave owns 2 adjacent rows (b,i),(b,i+1).
//   Each row is processed as a G-pass then an H-pass; each pass is a 2-deep
//   software pipeline of 2-load chunks (re+im f4). Live set ~50 VGPRs so
//   8 waves/SIMD fit; 2048 blocks = 8 blocks/CU all-resident.
__global__ __launch_bounds__(256) void k_step_main(
    const float* __restrict__ Gr, const float* __restrict__ Gi,
    const float* __restrict__ Hr, const float* __restrict__ Hi,
    const float* __restrict__ W1, const float* __restrict__ sReg,
    const float* __restrict__ sImg, float* __restrict__ gsR,
    float* __restrict__ gsI, float* __restrict__ hsR,
    float* __restrict__ hsI, float* __restrict__ hdyn) {
  const int t = threadIdx.x;
  const int blk = blockIdx.x;

  if (blk < kB * 2) {  // ---- hdyn path ----
    const int b = blk >> 1;
    const int hid = ((blk & 1) << 8) + t;
    const float* w1c = W1 + hid;
    const float* sr = sReg + b * kLs;
    const float* si = sImg + b * kLs;
    float acc = 0.f;
#pragma unroll 8
    for (int j = 0; j < kLs; ++j) {
      acc += sr[j] * w1c[(size_t)j * kHid];
      acc += si[j] * w1c[(size_t)(j + kLs) * kHid];
    }
    hdyn[b * kHid + hid] = acc;
    return;
  }

  // ---- matvec path ----
  const int mb = blk - kB * 2;            // 0..2047
  const int lane = t & 63;
  const int wv = t >> 6;
  const int gw = (mb << 2) + wv;          // 0..8191
  const int row0 = gw << 1;               // global row id (b*256+i), 2 rows
  const int b = row0 >> 8;

  float s_r[4], s_i[4];
#pragma unroll
  for (int rr = 0; rr < 4; ++rr) {
    s_r[rr] = sReg[(b << 8) + (rr << 6) + lane];
    s_i[rr] = sImg[(b << 8) + (rr << 6) + lane];
  }

  // one pass = complex matvec of one row of one matrix (re/im planes)
  auto pass = [&](const float* __restrict__ pr, const float* __restrict__ pi,
                  float* __restrict__ oR, float* __restrict__ oI,
                  size_t rb) {
    f4 cr0, ci0, cr1, ci1;
    cr0 = *(const f4*)(pr + rb);
    ci0 = *(const f4*)(pi + rb);
    f4 aR = {0, 0, 0, 0}, aI = {0, 0, 0, 0};
    // c=0: prefetch chunk1, compute chunk0
    cr1 = *(const f4*)(pr + rb + 256);
    ci1 = *(const f4*)(pi + rb + 256);
#pragma unroll
    for (int m = 0; m < kM; ++m) {
      aR[m] += cr0[m] * s_r[0] - ci0[m] * s_i[0];
      aI[m] += cr0[m] * s_i[0] + ci0[m] * s_r[0];
    }
    // c=1: prefetch chunk2, compute chunk1
    cr0 = *(const f4*)(pr + rb + 512);
    ci0 = *(const f4*)(pi + rb + 512);
#pragma unroll
    for (int m = 0; m < kM; ++m) {
      aR[m] += cr1[m] * s_r[1] - ci1[m] * s_i[1];
      aI[m] += cr1[m] * s_i[1] + ci1[m] * s_r[1];
    }
    // c=2: prefetch chunk3, compute chunk2
    cr1 = *(const f4*)(pr + rb + 768);
    ci1 = *(const f4*)(pi + rb + 768);
#pragma unroll
    for (int m = 0; m < kM; ++m) {
      aR[m] += cr0[m] * s_r[2] - ci0[m] * s_i[2];
      aI[m] += cr0[m] * s_i[2] + ci0[m] * s_r[2];
    }
    // c=3: compute chunk3
#pragma unroll
    for (int m = 0; m < kM; ++m) {
      aR[m] += cr1[m] * s_r[3] - ci1[m] * s_i[3];
      aI[m] += cr1[m] * s_i[3] + ci1[m] * s_r[3];
    }
#pragma unroll
    for (int m = 0; m < kM; ++m) {
      aR[m] = wred(aR[m]);
      aI[m] = wred(aI[m]);
    }
    if (lane == 0) {
      *(f4*)oR = aR;
      *(f4*)oI = aI;
    }
  };

  const size_t base = (size_t)row0 * (kLs * kM) + (size_t)(lane << 2);
  const size_t o0 = (size_t)row0 * kM;
  // row0
  pass(Gr, Gi, gsR + o0, gsI + o0, base);
  pass(Hr, Hi, hsR + o0, hsI + o0, base);
  // row1
  pass(Gr, Gi, gsR + o0 + kM, gsI + o0 + kM, base + kLs * kM);
  pass(Hr, Hi, hsR + o0 + kM, hsI + o0 + kM, base + kLs * kM);
}

// BN batch stats over b for each (m,hid). grid: 8 blocks x 256 threads.
__global__ __launch_bounds__(256) void k_bn(
    const float* __restrict__ hdyn, const float* __restrict__ hstat,
    float* __restrict__ mu_g, float* __restrict__ rs_g) {
  const int q = blockIdx.x * 256 + threadIdx.x;  // 0..2047
  const int m = q >> 9;
  const int hid = q & (kHid - 1);
  float sum = 0.f, ss = 0.f;
#pragma unroll 8
  for (int bb = 0; bb < kB; ++bb) {
    const float h = hdyn[bb * kHid + hid] + hstat[((size_t)bb * kM + m) * kHid + hid];
    sum += h;
    ss += h * h;
  }
  const float mu = sum * (1.f / kB);
  const float var = ss * (1.f / kB) - mu * mu;
  mu_g[q] = mu;
  rs_g[q] = rsqrtf(var + kEps);
}

// Per-step tail: one block per b. sGs/sHs, rho, eta_net, phi update,
// plus s(step+1) = exp(i*phi_new) and outS[step+1].
__global__ __launch_bounds__(256) void k_step_finish(
    const float* __restrict__ gsR, const float* __restrict__ gsI,
    const float* __restrict__ hsR, const float* __restrict__ hsI,
    const float* __restrict__ hdyn, const float* __restrict__ hstat,
    const float* __restrict__ mu_g, const float* __restrict__ rs_g,
    const float* __restrict__ gamma_, const float* __restrict__ beta_,
    const float* __restrict__ W2, const float* __restrict__ b2,
    float* __restrict__ phi, float* __restrict__ sReg, float* __restrict__ sImg,
    float* __restrict__ outSR, float* __restrict__ outSI,
    float* __restrict__ outRho, int step) {
  const int b = blockIdx.x, t = threadIdx.x;
  const int lane = t & 63, wv = t >> 6;
  __shared__ float red[4][16];
  __shared__ float sgR[4], sgI[4], shR[4], shI[4], c2[4];
  __shared__ float rho_s[4];

  const int idx = b * kLs + t;
  const float p = phi[idx];
  const float cs = sReg[idx];
  const float sn = sImg[idx];

  const size_t o = (size_t)idx * kM;
  const f4 gR = *(const f4*)(gsR + o);
  const f4 gI = *(const f4*)(gsI + o);
  const f4 hR = *(const f4*)(hsR + o);
  const f4 hI = *(const f4*)(hsI + o);

  // partials of sGs = sum_i conj(s_i)*Gs[i], sHs likewise
  float v[16];
#pragma unroll
  for (int m = 0; m < kM; ++m) {
    v[m] = cs * gR[m] + sn * gI[m];       // Re(conj(s)*Gs)
    v[4 + m] = cs * gI[m] - sn * gR[m];   // Im(conj(s)*Gs)
    v[8 + m] = cs * hR[m] + sn * hI[m];
    v[12 + m] = cs * hI[m] - sn * hR[m];
  }
#pragma unroll
  for (int k = 0; k < 16; ++k) v[k] = wred(v[k]);
  if (lane == 0) {
#pragma unroll
    for (int k = 0; k < 16; ++k) red[wv][k] = v[k];
  }
  __syncthreads();
  if (t == 0) {
#pragma unroll
    for (int m = 0; m < kM; ++m) {
      const float gr = red[0][m] + red[1][m] + red[2][m] + red[3][m];
      const float gi = red[0][4 + m] + red[1][4 + m] + red[2][4 + m] + red[3][4 + m];
      const float hr = red[0][8 + m] + red[1][8 + m] + red[2][8 + m] + red[3][8 + m];
      const float hi = red[0][12 + m] + red[1][12 + m] + red[2][12 + m] + red[3][12 + m];
      sgR[m] = gr; sgI[m] = gi; shR[m] = hr; shI[m] = hi;
      const float xr = hr * hr - hi * hi;   // Re(sHs^2)
      const float xi = 2.f * hr * hi;       // Im(sHs^2)
      c2[m] = 2.f * xr / (xr * xr + xi * xi);  // Re(2/sHs^2)
    }
  }
  __syncthreads();

  // rho[b,m] = sigmoid( relu(bn(h)) . W2 + b2 )
  float pm[4] = {0.f, 0.f, 0.f, 0.f};
#pragma unroll
  for (int kk = 0; kk < 2; ++kk) {
    const int hid = (kk << 8) + t;
    const float hd = hdyn[b * kHid + hid];
    const float ga = gamma_[hid], be = beta_[hid], w2 = W2[hid];
#pragma unroll
    for (int m = 0; m < kM; ++m) {
      const float h = hd + hstat[((size_t)b * kM + m) * kHid + hid];
      const int q = m * kHid + hid;
      float hn = ga * (h - mu_g[q]) * rs_g[q] + be;
      hn = fmaxf(hn, 0.f);
      pm[m] += hn * w2;
    }
  }
#pragma unroll
  for (int m = 0; m < kM; ++m) pm[m] = wred(pm[m]);
  if (lane == 0) {
#pragma unroll
    for (int m = 0; m < kM; ++m) red[wv][m] = pm[m];
  }
  __syncthreads();
  if (t < 4) {
    const float tot = red[0][t] + red[1][t] + red[2][t] + red[3][t] + b2[0];
    const float r = 1.f / (1.f + expf(-tot));
    rho_s[t] = r;
    outRho[((size_t)b * kSteps + step) * kM + t] = r;
  }
  __syncthreads();

  // eta_net[b,i=t] = sum_m c2[m] * Im((sHs*Gs - sGs*Hs)*conj(s_i)) * rho[m]
  float en = 0.f;
#pragma unroll
  for (int m = 0; m < kM; ++m) {
    const float ar = shR[m] * gR[m] - shI[m] * gI[m] - (sgR[m] * hR[m] - sgI[m] * hI[m]);
    const float ai = shR[m] * gI[m] + shI[m] * gR[m] - (sgR[m] * hI[m] + sgI[m] * hR[m]);
    en += c2[m] * (ai * cs - ar * sn) * rho_s[m];
  }
  const float pn = p - en;
  phi[idx] = pn;
  float sn2, cs2;
  sincosf(pn, &sn2, &cs2);
  sReg[idx] = cs2;
  sImg[idx] = sn2;
  const size_t oo = ((size_t)b * (kSteps + 1) + step + 1) * kLs + t;
  outSR[oo] = cs2;
  outSI[oo] = sn2;
}

extern "C" void kernel_launch(void* const* d_in, const int* in_sizes, int n_in,
                              void* d_out, int out_size, void* d_ws, size_t ws_size,
                              hipStream_t stream) {
  const float* phi_in = (const float*)d_in[0];
  const float* w_real = (const float*)d_in[1];
  const float* w_imag = (const float*)d_in[2];
  const float* y = (const float*)d_in[3];
  const float* G_real = (const float*)d_in[4];
  const float* G_imag = (const float*)d_in[5];
  const float* H_real = (const float*)d_in[6];
  const float* H_imag = (const float*)d_in[7];
  const float* W1 = (const float*)d_in[8];
  const float* b1 = (const float*)d_in[9];
  const float* gamma_ = (const float*)d_in[10];
  const float* beta_ = (const float*)d_in[11];
  const float* W2 = (const float*)d_in[12];
  const float* b2 = (const float*)d_in[13];

  float* ws = (float*)d_ws;
  float* phi = ws;                    // 16384
  float* gsR = phi + kB * kLs;        // 65536 each
  float* gsI = gsR + kB * kLs * kM;
  float* hsR = gsI + kB * kLs * kM;
  float* hsI = hsR + kB * kLs * kM;
  float* hdyn = hsI + kB * kLs * kM;  // 32768
  float* hstat = hdyn + kB * kHid;    // 131072
  float* mu_g = hstat + (size_t)kB * kM * kHid;  // 2048
  float* rs_g = mu_g + kM * kHid;                // 2048
  float* sReg = rs_g + kM * kHid;                // 16384
  float* sImg = sReg + kB * kLs;                 // 16384

  float* out = (float*)d_out;
  float* outSR = out;
  float* outSI = out + (size_t)kB * (kSteps + 1) * kLs;
  float* outRho = out + 2 * (size_t)kB * (kSteps + 1) * kLs;

  hipMemcpyAsync(phi, phi_in, (size_t)kB * kLs * sizeof(float),
                 hipMemcpyDeviceToDevice, stream);
  k_static<<<dim3(kB * 2), dim3(256), 0, stream>>>(w_real, w_imag, y, W1, b1, hstat);
  k_s0<<<dim3(kB), dim3(256), 0, stream>>>(phi, sReg, sImg, outSR, outSI);
  for (int step = 0; step < kSteps; ++step) {
    k_step_main<<<dim3(kB * 2 + 2048), dim3(256), 0, stream>>>(
        G_real, G_imag, H_real, H_imag, W1, sReg, sImg, gsR, gsI, hsR, hsI, hdyn);
    k_bn<<<dim3(kM * kHid / 256), dim3(256), 0, stream>>>(hdyn, hstat, mu_g, rs_g);
    k_step_finish<<<dim3(kB), dim3(256), 0, stream>>>(
        gsR, gsI, hsR, hsI, hdyn, hstat, mu_g, rs_g, gamma_, beta_, W2, b2,
        phi, sReg, sImg, outSR, outSI, outRho, step);
  }
}